// Round 7
// baseline (533.393 us; speedup 1.0000x reference)
//
#include <hip/hip_runtime.h>

typedef __bf16 bf16;
typedef __attribute__((ext_vector_type(8))) __bf16 bf16x8;
typedef __attribute__((ext_vector_type(4))) __bf16 bf16x4;
typedef __attribute__((ext_vector_type(2))) __bf16 bf16x2;
typedef __attribute__((ext_vector_type(4))) float f32x4;

#define DEVINL __device__ __forceinline__

// Async global->LDS, 16B per lane.
DEVINL void gload_lds16(const bf16* g, bf16* l) {
    __builtin_amdgcn_global_load_lds(
        (__attribute__((address_space(1))) unsigned int*)(unsigned long long)g,
        (__attribute__((address_space(3))) unsigned int*)l,
        16, 0, 0);
}

// XCD-aware swizzle (uniform work): contiguous by-slab per XCD, bx fastest.
DEVINL void xcd_swizzle(int& bx, int& by) {
    const int gx = gridDim.x, gy = gridDim.y;
    const int l = blockIdx.y * gx + blockIdx.x;
    const int xcd = l & 7;
    const int li = l >> 3;
    by = xcd * (gy >> 3) + li / gx;
    bx = li - (li / gx) * gx;
}

// Balanced XCD swizzle for causal grids (work ∝ by+1), gy==16 only:
// XCD x owns by = x and by = 15-x  ->  equal live-tile count per XCD.
DEVINL void xcd_swizzle_bal(int& bx, int& by) {
    const int gx = gridDim.x, gy = gridDim.y;
    const int l = blockIdx.y * gx + blockIdx.x;
    const int xcd = l & 7;
    const int li = l >> 3;
    const int j = li / gx;            // slab 0 or 1
    bx = li - j * gx;
    by = j ? (gy - 1 - xcd) : xcd;
}

// ---------------------------------------------------------------- converts
__global__ __launch_bounds__(256) void cvt3_f32_to_bf16(
    const float* __restrict__ a, const float* __restrict__ b,
    const float* __restrict__ c, bf16* __restrict__ out, int n4) {
    int i = blockIdx.x * blockDim.x + threadIdx.x;
    if (i >= n4) return;
    const float* src = (blockIdx.z == 0) ? a : (blockIdx.z == 1) ? b : c;
    bf16* dst = out + (size_t)blockIdx.z * (size_t)n4 * 4;
    float4 f = ((const float4*)src)[i];
    bf16x4 o;
    o.x = (bf16)f.x; o.y = (bf16)f.y; o.z = (bf16)f.z; o.w = (bf16)f.w;
    ((bf16x4*)dst)[i] = o;
}

__global__ __launch_bounds__(256) void cvt4_f32_to_bf16(
    const float* __restrict__ a, const float* __restrict__ b,
    const float* __restrict__ c, const float* __restrict__ d,
    bf16* __restrict__ out, int n4) {
    int i = blockIdx.x * blockDim.x + threadIdx.x;
    if (i >= n4) return;
    const float* src = (blockIdx.z == 0) ? a : (blockIdx.z == 1) ? b
                     : (blockIdx.z == 2) ? c : d;
    bf16* dst = out + (size_t)blockIdx.z * (size_t)n4 * 4;
    float4 f = ((const float4*)src)[i];
    bf16x4 o;
    o.x = (bf16)f.x; o.y = (bf16)f.y; o.z = (bf16)f.z; o.w = (bf16)f.w;
    ((bf16x4*)dst)[i] = o;
}

// ---------------------------------------------------------------- transpose
__global__ __launch_bounds__(256) void transpose_bf16(
    const unsigned short* __restrict__ in, unsigned short* __restrict__ out,
    int R, int C) {
    __shared__ unsigned short t[64][65];
    const size_t bo = (size_t)blockIdx.z * R * C;
    const int r0 = blockIdx.y * 64, c0 = blockIdx.x * 64;
#pragma unroll
    for (int i = 0; i < 16; i++) {
        int lin = threadIdx.x + i * 256;
        int r = lin >> 6, c = lin & 63;
        t[r][c] = in[bo + (size_t)(r0 + r) * C + (c0 + c)];
    }
    __syncthreads();
#pragma unroll
    for (int i = 0; i < 16; i++) {
        int lin = threadIdx.x + i * 256;
        int r = lin >> 6, c = lin & 63;
        out[bo + (size_t)(c0 + r) * R + (r0 + c)] = t[c][r];
    }
}

// ---------------------------------------------------------------- bias fold
// bout[e] = dot(Wo[e,:], bv) + bo[e]   (one wave per e)
__global__ __launch_bounds__(256) void bias_fold(
    const float* __restrict__ Wo, const float* __restrict__ bv,
    const float* __restrict__ bo, float* __restrict__ bout) {
    const int e = blockIdx.x * 4 + (threadIdx.x >> 6);
    const int lane = threadIdx.x & 63;
    float s = 0.f;
    for (int k = lane; k < 1024; k += 64) s += Wo[e * 1024 + k] * bv[k];
#pragma unroll
    for (int off = 32; off > 0; off >>= 1) s += __shfl_xor(s, off, 64);
    if (lane == 0) bout[e] = s + bo[e];
}

// ------------------------------- GEMM 128x128, BK=32, LDS dbuf + XOR swizzle
template <int EPI>
__global__ __launch_bounds__(256) void gemm_bt128(
    const bf16* __restrict__ A, const bf16* __restrict__ B,
    const float* __restrict__ bias0, const float* __restrict__ bias1,
    const float* __restrict__ bias2, void* __restrict__ Cv,
    int M, int N, int K,
    long long sA, long long sB, long long sC,
    float scale) {
    int bx, by;
    xcd_swizzle(bx, by);
    const int bz = blockIdx.z;
    const int m0 = by * 128, n0 = bx * 128;

    A += (size_t)bz * sA;
    B += (size_t)bz * sB;
    const float* bias = (bz == 0) ? bias0 : (bz == 1) ? bias1 : bias2;

    __shared__ __align__(16) bf16 As[2][128 * 32];
    __shared__ __align__(16) bf16 Bs[2][128 * 32];

    const int tid = threadIdx.x;
    const int wave = tid >> 6;
    const int lane = tid & 63;
    const int lr = lane & 15;
    const int lq = lane >> 4;
    const int wm = (wave >> 1) * 64;
    const int wn = (wave & 1) * 64;
    const int srow = lane >> 2;
    const int scol = ((lane & 3) ^ ((lane >> 3) & 3)) * 8;

    const bf16* gA = A + (size_t)(m0 + wave * 16 + srow) * K + scol;
    const bf16* gB = B + (size_t)(n0 + wave * 16 + srow) * K + scol;
    const size_t rowskip = (size_t)64 * K;
    const int rsw = (lq ^ ((lr >> 1) & 3)) * 8;

    f32x4 acc[4][4];
    const f32x4 fzero = {0.f, 0.f, 0.f, 0.f};
#pragma unroll
    for (int i = 0; i < 4; i++)
#pragma unroll
        for (int j = 0; j < 4; j++) acc[i][j] = fzero;

#define STAGE128(bufi)                                          \
    do {                                                        \
        gload_lds16(gA,           As[bufi] + wave * 512);       \
        gload_lds16(gA + rowskip, As[bufi] + (wave + 4) * 512); \
        gload_lds16(gB,           Bs[bufi] + wave * 512);       \
        gload_lds16(gB + rowskip, Bs[bufi] + (wave + 4) * 512); \
        gA += 32; gB += 32;                                     \
    } while (0)

    STAGE128(0);
    int cur = 0;
    for (int k0 = 0; k0 < K; k0 += 32) {
        __syncthreads();
        if (k0 + 32 < K) STAGE128(cur ^ 1);

        bf16x8 af[4], bfr[4];
#pragma unroll
        for (int i = 0; i < 4; i++)
            af[i] = *(const bf16x8*)(As[cur] + (wm + i * 16 + lr) * 32 + rsw);
#pragma unroll
        for (int j = 0; j < 4; j++)
            bfr[j] = *(const bf16x8*)(Bs[cur] + (wn + j * 16 + lr) * 32 + rsw);
#pragma unroll
        for (int i = 0; i < 4; i++)
#pragma unroll
            for (int j = 0; j < 4; j++)
                acc[i][j] = __builtin_amdgcn_mfma_f32_16x16x32_bf16(
                    af[i], bfr[j], acc[i][j], 0, 0, 0);
        cur ^= 1;
    }
#undef STAGE128

#pragma unroll
    for (int j = 0; j < 4; j++) {
        const int col = n0 + wn + j * 16 + lr;
        const float bb = bias ? bias[col] : 0.0f;
#pragma unroll
        for (int i = 0; i < 4; i++) {
            const int rowb = m0 + wm + i * 16 + lq * 4;
#pragma unroll
            for (int r = 0; r < 4; r++) {
                if (EPI == 0)
                    ((bf16*)Cv)[(size_t)bz * sC + (size_t)(rowb + r) * N + col] =
                        (bf16)(acc[i][j][r] * scale + bb);
                else
                    ((float*)Cv)[(size_t)bz * sC + (size_t)(rowb + r) * N + col] =
                        acc[i][j][r] * scale + bb;
            }
        }
    }
}

// ------------------------------- GEMM 128x128, register-direct (no LDS!)
// Fragments are K-contiguous for the B^T layout, so each wave loads its MFMA
// fragments straight from global into VGPRs: no LDS, no __syncthreads in the
// K-loop; loads are vmcnt-gated per-wave, pipelined 1.5 stages deep.
// causal 1: skip tiles above diagonal; 2: trim K to m0+128. Requires K%64==0,
// gridDim.y==16 (balanced swizzle).
template <int EPI>
__global__ __launch_bounds__(256) void gemm_reg(
    const bf16* __restrict__ A, const bf16* __restrict__ B,
    const float* __restrict__ bias, void* __restrict__ Cv,
    int M, int N, int K,
    long long sA, long long sB, long long sC,
    float scale, int causal) {
    int bx, by;
    xcd_swizzle_bal(bx, by);
    const int bz = blockIdx.z;
    const int m0 = by * 128, n0 = bx * 128;
    if (causal == 1 && n0 > m0) return;
    int Keff = K;
    if (causal == 2) { Keff = m0 + 128; if (Keff > K) Keff = K; }

    const int lane = threadIdx.x & 63;
    const int wave = threadIdx.x >> 6;
    const int lr = lane & 15;
    const int lq = lane >> 4;
    const int wm = (wave >> 1) * 64;
    const int wn = (wave & 1) * 64;

    const bf16* pa = A + (size_t)bz * sA + (size_t)(m0 + wm + lr) * K + lq * 8;
    const bf16* pb = B + (size_t)bz * sB + (size_t)(n0 + wn + lr) * K + lq * 8;
    const size_t rs = (size_t)16 * K;

    f32x4 acc[4][4];
    const f32x4 fzero = {0.f, 0.f, 0.f, 0.f};
#pragma unroll
    for (int i = 0; i < 4; i++)
#pragma unroll
        for (int j = 0; j < 4; j++) acc[i][j] = fzero;

    bf16x8 a0[4], b0[4], a1[4], b1[4];

#define LDFR(ar, br, koff)                                         \
    do {                                                           \
        _Pragma("unroll") for (int i = 0; i < 4; i++) {            \
            ar[i] = *(const bf16x8*)(pa + (size_t)i * rs + (koff)); \
            br[i] = *(const bf16x8*)(pb + (size_t)i * rs + (koff)); \
        }                                                          \
    } while (0)

#define MF16(ar, br)                                               \
    do {                                                           \
        _Pragma("unroll") for (int i = 0; i < 4; i++)              \
            _Pragma("unroll") for (int j = 0; j < 4; j++)          \
                acc[i][j] = __builtin_amdgcn_mfma_f32_16x16x32_bf16( \
                    ar[i], br[j], acc[i][j], 0, 0, 0);             \
    } while (0)

    LDFR(a0, b0, 0);
    for (int k0 = 0; k0 < Keff; k0 += 64) {
        LDFR(a1, b1, k0 + 32);
        MF16(a0, b0);
        if (k0 + 64 < Keff) LDFR(a0, b0, k0 + 64);
        MF16(a1, b1);
    }
#undef LDFR
#undef MF16

#pragma unroll
    for (int j = 0; j < 4; j++) {
        const int col = n0 + wn + j * 16 + lr;
        const float bb = bias ? bias[col] : 0.0f;
#pragma unroll
        for (int i = 0; i < 4; i++) {
            const int rowb = m0 + wm + i * 16 + lq * 4;
#pragma unroll
            for (int r = 0; r < 4; r++) {
                if (EPI == 0)
                    ((bf16*)Cv)[(size_t)bz * sC + (size_t)(rowb + r) * N + col] =
                        (bf16)(acc[i][j][r] * scale + bb);
                else
                    ((float*)Cv)[(size_t)bz * sC + (size_t)(rowb + r) * N + col] =
                        acc[i][j][r] * scale + bb;
            }
        }
    }
}

// ---------------------------------------------------------------- softmax
__global__ __launch_bounds__(256) void softmax_causal(
    const bf16* __restrict__ Sc, bf16* __restrict__ P, int S) {
    const int row = blockIdx.x;          // b*S + q
    const int q = row & (S - 1);
    const bf16* src = Sc + (size_t)row * S;
    bf16* dst = P + (size_t)row * S;
    const int L = q + 1;
    const int tid = threadIdx.x;

    float v[8];
    float mx = -3.0e38f;
#pragma unroll
    for (int i = 0; i < 4; i++) {
        int k = (i * 256 + tid) * 2;
        bf16x2 u = ((const bf16x2*)src)[i * 256 + tid];
        v[2 * i]     = (k < L)     ? (float)u.x : -3.0e38f;
        v[2 * i + 1] = (k + 1 < L) ? (float)u.y : -3.0e38f;
        mx = fmaxf(mx, fmaxf(v[2 * i], v[2 * i + 1]));
    }
#pragma unroll
    for (int off = 32; off > 0; off >>= 1) mx = fmaxf(mx, __shfl_xor(mx, off, 64));
    __shared__ float redm[4], reds[4];
    if ((tid & 63) == 0) redm[tid >> 6] = mx;
    __syncthreads();
    mx = fmaxf(fmaxf(redm[0], redm[1]), fmaxf(redm[2], redm[3]));

    float sum = 0.f;
#pragma unroll
    for (int i = 0; i < 8; i++) {
        float e = (v[i] > -1.0e38f) ? __expf(v[i] - mx) : 0.f;
        v[i] = e;
        sum += e;
    }
#pragma unroll
    for (int off = 32; off > 0; off >>= 1) sum += __shfl_xor(sum, off, 64);
    if ((tid & 63) == 0) reds[tid >> 6] = sum;
    __syncthreads();
    sum = reds[0] + reds[1] + reds[2] + reds[3];
    const float inv = 1.0f / sum;
#pragma unroll
    for (int i = 0; i < 4; i++) {
        bf16x2 o;
        o.x = (bf16)(v[2 * i] * inv);
        o.y = (bf16)(v[2 * i + 1] * inv);
        ((bf16x2*)dst)[i * 256 + tid] = o;
    }
}

// ---------------------------------------------------------------- launch
extern "C" void kernel_launch(void* const* d_in, const int* in_sizes, int n_in,
                              void* d_out, int out_size, void* d_ws, size_t ws_size,
                              hipStream_t stream) {
    const int B = 4, S = 2048, E = 1024;
    const size_t SBE = (size_t)B * S * E;   // 8,388,608
    const size_t EE = (size_t)E * E;        // 1,048,576

    const float* q_in = (const float*)d_in[0];
    const float* k_in = (const float*)d_in[1];
    const float* v_in = (const float*)d_in[2];
    // d_in[3] = mask (tril) — causality handled by index math
    const float* Wq = (const float*)d_in[4];
    const float* bq = (const float*)d_in[5];
    const float* Wk = (const float*)d_in[6];
    const float* bk = (const float*)d_in[7];
    const float* Wv = (const float*)d_in[8];
    const float* bv = (const float*)d_in[9];
    const float* Wo = (const float*)d_in[10];
    const float* bo = (const float*)d_in[11];

    char* ws = (char*)d_ws;
    // Region A (64 MiB), time-multiplexed:
    //   [0,48M): qkvb (phase 1) then Sc bf16 [0,32M) (phase 2)
    //   [48M,50M): WvT (bf16 Wv^T, live steps 3-4)
    //   [50M,+4KB): bout
    bf16* qkvb = (bf16*)ws;
    bf16* Sc = (bf16*)ws;
    bf16* WvT = (bf16*)(ws + 3 * SBE * 2);
    float* bout = (float*)(ws + 3 * SBE * 2 + EE * 2);
    char* p = ws + (size_t)B * S * S * 4;
    bf16* QKVb = (bf16*)p; p += 3 * SBE * 2;   // Qb|Kb|VW contiguous
    bf16* VWt = (bf16*)p; p += SBE * 2;
    bf16* Pb = (bf16*)p; p += (size_t)B * S * S * 2;
    bf16* Wb = (bf16*)p; p += 4 * EE * 2;      // Wq|Wk|Wv(->Wvo)|Wo

    bf16* Qb = QKVb;
    bf16* Kb = QKVb + SBE;
    bf16* VW = QKVb + 2 * SBE;
    bf16* Wob = Wb + 3 * EE;
    bf16* Wvo = Wb + 2 * EE;   // Wv slot is overwritten by Wvo after transpose

    dim3 blk(256);

    // 1. converts
    dim3 gcvt3((int)(SBE / 4 / 256), 1, 3);
    cvt3_f32_to_bf16<<<gcvt3, blk, 0, stream>>>(q_in, k_in, v_in, qkvb, (int)(SBE / 4));
    dim3 gcvt4((int)(EE / 4 / 256), 1, 4);
    cvt4_f32_to_bf16<<<gcvt4, blk, 0, stream>>>(Wq, Wk, Wv, Wo, Wb, (int)(EE / 4));

    // 2. WvT = Wv^T ; Wvo = Wo @ Wv (via B^T GEMM with B=WvT) ; bout = Wo bv + bo
    dim3 gtw(16, 16, 1);
    transpose_bf16<<<gtw, blk, 0, stream>>>((const unsigned short*)(Wb + 2 * EE),
                                            (unsigned short*)WvT, E, E);
    dim3 gwvo(E / 128, E / 128, 1);
    gemm_bt128<0><<<gwvo, blk, 0, stream>>>(Wob, WvT, nullptr, nullptr, nullptr,
                                            Wvo, E, E, E, 0, 0, 0, 1.f);
    bias_fold<<<256, blk, 0, stream>>>(Wo, bv, bo, bout);

    // 3. fused projections: z=0 Q (bq), z=1 K (bk), z=2 VW = v_in @ Wvo^T (no bias)
    dim3 gproj(E / 128, (B * S) / 128, 3);
    gemm_bt128<0><<<gproj, blk, 0, stream>>>(qkvb, Wb, bq, bk, nullptr, QKVb,
                                             B * S, E, E,
                                             (long long)SBE, (long long)EE,
                                             (long long)SBE, 1.f);

    // 4. VW^T per batch: [S,E] -> [E,S]
    dim3 gt(E / 64, S / 64, B);
    transpose_bf16<<<gt, blk, 0, stream>>>((const unsigned short*)VW,
                                           (unsigned short*)VWt, S, E);

    // 5. scores = Q K^T / 32 -> bf16 (register-direct GEMM, causal skip)
    dim3 gsc(S / 128, S / 128, B);
    gemm_reg<0><<<gsc, blk, 0, stream>>>(Qb, Kb, nullptr, Sc, S, S, E,
                                         (long long)S * E, (long long)S * E,
                                         (long long)S * S, 0.03125f, 1);

    // 6. causal softmax -> bf16 probs (zeros above diagonal)
    softmax_causal<<<B * S, blk, 0, stream>>>(Sc, Pb, S);

    // 7. out = P @ VW + bout (register-direct GEMM, K trimmed causally, fp32)
    dim3 gpv(E / 128, S / 128, B);
    gemm_reg<1><<<gpv, blk, 0, stream>>>(Pb, VWt, bout, (float*)d_out, S, E, S,
                                         (long long)S * S, (long long)E * S,
                                         (long long)S * E, 1.f, 2);
}

// Round 8
// 405.590 us; speedup vs baseline: 1.3151x; 1.3151x over previous
//
#include <hip/hip_runtime.h>

typedef __bf16 bf16;
typedef __attribute__((ext_vector_type(8))) __bf16 bf16x8;
typedef __attribute__((ext_vector_type(4))) __bf16 bf16x4;
typedef __attribute__((ext_vector_type(2))) __bf16 bf16x2;
typedef __attribute__((ext_vector_type(4))) float f32x4;

#define DEVINL __device__ __forceinline__

// Async global->LDS, 16B per lane.
DEVINL void gload_lds16(const bf16* g, bf16* l) {
    __builtin_amdgcn_global_load_lds(
        (__attribute__((address_space(1))) unsigned int*)(unsigned long long)g,
        (__attribute__((address_space(3))) unsigned int*)l,
        16, 0, 0);
}

// XCD-aware swizzle (uniform work): contiguous by-slab per XCD, bx fastest.
// Requires gridDim.y % 8 == 0.
DEVINL void xcd_swizzle(int& bx, int& by) {
    const int gx = gridDim.x, gy = gridDim.y;
    const int l = blockIdx.y * gx + blockIdx.x;
    const int xcd = l & 7;
    const int li = l >> 3;
    by = xcd * (gy >> 3) + li / gx;
    bx = li - (li / gx) * gx;
}

// Balanced XCD swizzle for causal grids (work ∝ by+1), gridDim.y==16 only:
// XCD x owns by = x and by = 15-x  ->  equal live work per XCD.
DEVINL void xcd_swizzle_bal(int& bx, int& by) {
    const int gx = gridDim.x, gy = gridDim.y;
    const int l = blockIdx.y * gx + blockIdx.x;
    const int xcd = l & 7;
    const int li = l >> 3;
    const int j = li / gx;            // slab 0 or 1
    bx = li - j * gx;
    by = j ? (gy - 1 - xcd) : xcd;
}

// ---------------------------------------------------------------- converts
__global__ __launch_bounds__(256) void cvt3_f32_to_bf16(
    const float* __restrict__ a, const float* __restrict__ b,
    const float* __restrict__ c, bf16* __restrict__ out, int n4) {
    int i = blockIdx.x * blockDim.x + threadIdx.x;
    if (i >= n4) return;
    const float* src = (blockIdx.z == 0) ? a : (blockIdx.z == 1) ? b : c;
    bf16* dst = out + (size_t)blockIdx.z * (size_t)n4 * 4;
    float4 f = ((const float4*)src)[i];
    bf16x4 o;
    o.x = (bf16)f.x; o.y = (bf16)f.y; o.z = (bf16)f.z; o.w = (bf16)f.w;
    ((bf16x4*)dst)[i] = o;
}

__global__ __launch_bounds__(256) void cvt4_f32_to_bf16(
    const float* __restrict__ a, const float* __restrict__ b,
    const float* __restrict__ c, const float* __restrict__ d,
    bf16* __restrict__ out, int n4) {
    int i = blockIdx.x * blockDim.x + threadIdx.x;
    if (i >= n4) return;
    const float* src = (blockIdx.z == 0) ? a : (blockIdx.z == 1) ? b
                     : (blockIdx.z == 2) ? c : d;
    bf16* dst = out + (size_t)blockIdx.z * (size_t)n4 * 4;
    float4 f = ((const float4*)src)[i];
    bf16x4 o;
    o.x = (bf16)f.x; o.y = (bf16)f.y; o.z = (bf16)f.z; o.w = (bf16)f.w;
    ((bf16x4*)dst)[i] = o;
}

// ---------------------------------------------------------------- transpose
__global__ __launch_bounds__(256) void transpose_bf16(
    const unsigned short* __restrict__ in, unsigned short* __restrict__ out,
    int R, int C) {
    __shared__ unsigned short t[64][65];
    const size_t bo = (size_t)blockIdx.z * R * C;
    const int r0 = blockIdx.y * 64, c0 = blockIdx.x * 64;
#pragma unroll
    for (int i = 0; i < 16; i++) {
        int lin = threadIdx.x + i * 256;
        int r = lin >> 6, c = lin & 63;
        t[r][c] = in[bo + (size_t)(r0 + r) * C + (c0 + c)];
    }
    __syncthreads();
#pragma unroll
    for (int i = 0; i < 16; i++) {
        int lin = threadIdx.x + i * 256;
        int r = lin >> 6, c = lin & 63;
        out[bo + (size_t)(c0 + r) * R + (r0 + c)] = t[c][r];
    }
}

// ---------------------------------------------------------------- bias fold
// bout[e] = dot(Wo[e,:], bv) + bo[e]   (one wave per e)
__global__ __launch_bounds__(256) void bias_fold(
    const float* __restrict__ Wo, const float* __restrict__ bv,
    const float* __restrict__ bo, float* __restrict__ bout) {
    const int e = blockIdx.x * 4 + (threadIdx.x >> 6);
    const int lane = threadIdx.x & 63;
    float s = 0.f;
    for (int k = lane; k < 1024; k += 64) s += Wo[e * 1024 + k] * bv[k];
#pragma unroll
    for (int off = 32; off > 0; off >>= 1) s += __shfl_xor(s, off, 64);
    if (lane == 0) bout[e] = s + bo[e];
}

// ------------------------------- GEMM 128x128, BK=32, LDS dbuf + XOR swizzle
template <int EPI>
__global__ __launch_bounds__(256) void gemm_bt128(
    const bf16* __restrict__ A, const bf16* __restrict__ B,
    const float* __restrict__ bias0, const float* __restrict__ bias1,
    const float* __restrict__ bias2, void* __restrict__ Cv,
    int M, int N, int K,
    long long sA, long long sB, long long sC,
    float scale) {
    int bx, by;
    xcd_swizzle(bx, by);
    const int bz = blockIdx.z;
    const int m0 = by * 128, n0 = bx * 128;

    A += (size_t)bz * sA;
    B += (size_t)bz * sB;
    const float* bias = (bz == 0) ? bias0 : (bz == 1) ? bias1 : bias2;

    __shared__ __align__(16) bf16 As[2][128 * 32];
    __shared__ __align__(16) bf16 Bs[2][128 * 32];

    const int tid = threadIdx.x;
    const int wave = tid >> 6;
    const int lane = tid & 63;
    const int lr = lane & 15;
    const int lq = lane >> 4;
    const int wm = (wave >> 1) * 64;
    const int wn = (wave & 1) * 64;
    const int srow = lane >> 2;
    const int scol = ((lane & 3) ^ ((lane >> 3) & 3)) * 8;

    const bf16* gA = A + (size_t)(m0 + wave * 16 + srow) * K + scol;
    const bf16* gB = B + (size_t)(n0 + wave * 16 + srow) * K + scol;
    const size_t rowskip = (size_t)64 * K;
    const int rsw = (lq ^ ((lr >> 1) & 3)) * 8;

    f32x4 acc[4][4];
    const f32x4 fzero = {0.f, 0.f, 0.f, 0.f};
#pragma unroll
    for (int i = 0; i < 4; i++)
#pragma unroll
        for (int j = 0; j < 4; j++) acc[i][j] = fzero;

#define STAGE128(bufi)                                          \
    do {                                                        \
        gload_lds16(gA,           As[bufi] + wave * 512);       \
        gload_lds16(gA + rowskip, As[bufi] + (wave + 4) * 512); \
        gload_lds16(gB,           Bs[bufi] + wave * 512);       \
        gload_lds16(gB + rowskip, Bs[bufi] + (wave + 4) * 512); \
        gA += 32; gB += 32;                                     \
    } while (0)

    STAGE128(0);
    int cur = 0;
    for (int k0 = 0; k0 < K; k0 += 32) {
        __syncthreads();
        if (k0 + 32 < K) STAGE128(cur ^ 1);

        bf16x8 af[4], bfr[4];
#pragma unroll
        for (int i = 0; i < 4; i++)
            af[i] = *(const bf16x8*)(As[cur] + (wm + i * 16 + lr) * 32 + rsw);
#pragma unroll
        for (int j = 0; j < 4; j++)
            bfr[j] = *(const bf16x8*)(Bs[cur] + (wn + j * 16 + lr) * 32 + rsw);
#pragma unroll
        for (int i = 0; i < 4; i++)
#pragma unroll
            for (int j = 0; j < 4; j++)
                acc[i][j] = __builtin_amdgcn_mfma_f32_16x16x32_bf16(
                    af[i], bfr[j], acc[i][j], 0, 0, 0);
        cur ^= 1;
    }
#undef STAGE128

#pragma unroll
    for (int j = 0; j < 4; j++) {
        const int col = n0 + wn + j * 16 + lr;
        const float bb = bias ? bias[col] : 0.0f;
#pragma unroll
        for (int i = 0; i < 4; i++) {
            const int rowb = m0 + wm + i * 16 + lq * 4;
#pragma unroll
            for (int r = 0; r < 4; r++) {
                if (EPI == 0)
                    ((bf16*)Cv)[(size_t)bz * sC + (size_t)(rowb + r) * N + col] =
                        (bf16)(acc[i][j][r] * scale + bb);
                else
                    ((float*)Cv)[(size_t)bz * sC + (size_t)(rowb + r) * N + col] =
                        acc[i][j][r] * scale + bb;
            }
        }
    }
}

// ------------------------------- GEMM 128x64, BK=32, dbuf + LDS-XOR swizzle
// causal 1: skip tiles fully above diagonal; 2: trim K to m0+128 (PV).
// Causal grids (gy==16) use the balanced XCD swizzle.
template <int EPI>
__global__ __launch_bounds__(256) void gemm_bt64(
    const bf16* __restrict__ A, const bf16* __restrict__ B,
    const float* __restrict__ bias, void* __restrict__ Cv,
    int M, int N, int K,
    long long sA, long long sB, long long sC,
    float scale, int causal) {
    int bx, by;
    if (causal) xcd_swizzle_bal(bx, by);
    else        xcd_swizzle(bx, by);
    const int bz = blockIdx.z;
    const int m0 = by * 128, n0 = bx * 64;
    if (causal == 1 && n0 > m0 + 127) return;
    int Keff = K;
    if (causal == 2) { Keff = m0 + 128; if (Keff > K) Keff = K; }

    A += (size_t)bz * sA;
    B += (size_t)bz * sB;

    __shared__ __align__(16) bf16 As[2][128 * 32];
    __shared__ __align__(16) bf16 Bs[2][64 * 32];

    const int tid = threadIdx.x;
    const int wave = tid >> 6;
    const int lane = tid & 63;
    const int lr = lane & 15;
    const int lq = lane >> 4;
    const int wm = wave * 32;
    const int srow = lane >> 2;
    const int scol = ((lane & 3) ^ ((lane >> 3) & 3)) * 8;

    const bf16* gA = A + (size_t)(m0 + wave * 16 + srow) * K + scol;
    const bf16* gB = B + (size_t)(n0 + wave * 16 + srow) * K + scol;
    const size_t rowskip = (size_t)64 * K;
    const int rsw = (lq ^ ((lr >> 1) & 3)) * 8;

    f32x4 acc[2][4];
    const f32x4 fzero = {0.f, 0.f, 0.f, 0.f};
#pragma unroll
    for (int i = 0; i < 2; i++)
#pragma unroll
        for (int j = 0; j < 4; j++) acc[i][j] = fzero;

#define STAGE64(bufi)                                           \
    do {                                                        \
        gload_lds16(gA,           As[bufi] + wave * 512);       \
        gload_lds16(gA + rowskip, As[bufi] + (wave + 4) * 512); \
        gload_lds16(gB,           Bs[bufi] + wave * 512);       \
        gA += 32; gB += 32;                                     \
    } while (0)

    STAGE64(0);
    int cur = 0;
    for (int k0 = 0; k0 < Keff; k0 += 32) {
        __syncthreads();
        if (k0 + 32 < Keff) STAGE64(cur ^ 1);

        bf16x8 af[2], bfr[4];
#pragma unroll
        for (int i = 0; i < 2; i++)
            af[i] = *(const bf16x8*)(As[cur] + (wm + i * 16 + lr) * 32 + rsw);
#pragma unroll
        for (int j = 0; j < 4; j++)
            bfr[j] = *(const bf16x8*)(Bs[cur] + (j * 16 + lr) * 32 + rsw);
#pragma unroll
        for (int i = 0; i < 2; i++)
#pragma unroll
            for (int j = 0; j < 4; j++)
                acc[i][j] = __builtin_amdgcn_mfma_f32_16x16x32_bf16(
                    af[i], bfr[j], acc[i][j], 0, 0, 0);
        cur ^= 1;
    }
#undef STAGE64

#pragma unroll
    for (int j = 0; j < 4; j++) {
        const int col = n0 + j * 16 + lr;
        const float bb = bias ? bias[col] : 0.0f;
#pragma unroll
        for (int i = 0; i < 2; i++) {
            const int rowb = m0 + wm + i * 16 + lq * 4;
#pragma unroll
            for (int r = 0; r < 4; r++) {
                if (EPI == 0)
                    ((bf16*)Cv)[(size_t)bz * sC + (size_t)(rowb + r) * N + col] =
                        (bf16)(acc[i][j][r] * scale + bb);
                else
                    ((float*)Cv)[(size_t)bz * sC + (size_t)(rowb + r) * N + col] =
                        acc[i][j][r] * scale + bb;
            }
        }
    }
}

// ---------------------------------------------------------------- softmax
__global__ __launch_bounds__(256) void softmax_causal(
    const bf16* __restrict__ Sc, bf16* __restrict__ P, int S) {
    const int row = blockIdx.x;          // b*S + q
    const int q = row & (S - 1);
    const bf16* src = Sc + (size_t)row * S;
    bf16* dst = P + (size_t)row * S;
    const int L = q + 1;
    const int tid = threadIdx.x;

    float v[8];
    float mx = -3.0e38f;
#pragma unroll
    for (int i = 0; i < 4; i++) {
        int k = (i * 256 + tid) * 2;
        bf16x2 u = ((const bf16x2*)src)[i * 256 + tid];
        v[2 * i]     = (k < L)     ? (float)u.x : -3.0e38f;
        v[2 * i + 1] = (k + 1 < L) ? (float)u.y : -3.0e38f;
        mx = fmaxf(mx, fmaxf(v[2 * i], v[2 * i + 1]));
    }
#pragma unroll
    for (int off = 32; off > 0; off >>= 1) mx = fmaxf(mx, __shfl_xor(mx, off, 64));
    __shared__ float redm[4], reds[4];
    if ((tid & 63) == 0) redm[tid >> 6] = mx;
    __syncthreads();
    mx = fmaxf(fmaxf(redm[0], redm[1]), fmaxf(redm[2], redm[3]));

    float sum = 0.f;
#pragma unroll
    for (int i = 0; i < 8; i++) {
        float e = (v[i] > -1.0e38f) ? __expf(v[i] - mx) : 0.f;
        v[i] = e;
        sum += e;
    }
#pragma unroll
    for (int off = 32; off > 0; off >>= 1) sum += __shfl_xor(sum, off, 64);
    if ((tid & 63) == 0) reds[tid >> 6] = sum;
    __syncthreads();
    sum = reds[0] + reds[1] + reds[2] + reds[3];
    const float inv = 1.0f / sum;
#pragma unroll
    for (int i = 0; i < 4; i++) {
        bf16x2 o;
        o.x = (bf16)(v[2 * i] * inv);
        o.y = (bf16)(v[2 * i + 1] * inv);
        ((bf16x2*)dst)[i * 256 + tid] = o;
    }
}

// ---------------------------------------------------------------- launch
extern "C" void kernel_launch(void* const* d_in, const int* in_sizes, int n_in,
                              void* d_out, int out_size, void* d_ws, size_t ws_size,
                              hipStream_t stream) {
    const int B = 4, S = 2048, E = 1024;
    const size_t SBE = (size_t)B * S * E;   // 8,388,608
    const size_t EE = (size_t)E * E;        // 1,048,576

    const float* q_in = (const float*)d_in[0];
    const float* k_in = (const float*)d_in[1];
    const float* v_in = (const float*)d_in[2];
    // d_in[3] = mask (tril) — causality handled by index math
    const float* Wq = (const float*)d_in[4];
    const float* bq = (const float*)d_in[5];
    const float* Wk = (const float*)d_in[6];
    const float* bk = (const float*)d_in[7];
    const float* Wv = (const float*)d_in[8];
    const float* bv = (const float*)d_in[9];
    const float* Wo = (const float*)d_in[10];
    const float* bo = (const float*)d_in[11];

    char* ws = (char*)d_ws;
    // Region A (67 MB), time-multiplexed:
    //   [0,48M): qkvb (phase 1), then Sc bf16 [0,33.5M) (phase 2)
    //   [48M,50M): WvT (bf16 Wv^T, live during Wvo prep)
    //   [50M,+4KB): bout
    bf16* qkvb = (bf16*)ws;
    bf16* Sc = (bf16*)ws;
    bf16* WvT = (bf16*)(ws + 3 * SBE * 2);
    float* bout = (float*)(ws + 3 * SBE * 2 + EE * 2);
    char* p = ws + (size_t)B * S * S * 4;
    bf16* QKVb = (bf16*)p; p += 3 * SBE * 2;   // Qb|Kb|VW contiguous
    bf16* VWt = (bf16*)p; p += SBE * 2;
    bf16* Pb = (bf16*)p; p += (size_t)B * S * S * 2;
    bf16* Wb = (bf16*)p; p += 4 * EE * 2;      // Wq|Wk|Wv(->Wvo)|Wo

    bf16* Qb = QKVb;
    bf16* Kb = QKVb + SBE;
    bf16* VW = QKVb + 2 * SBE;
    bf16* Wob = Wb + 3 * EE;
    bf16* Wvo = Wb + 2 * EE;   // Wv slot overwritten by Wvo after transpose

    dim3 blk(256);

    // 1. converts
    dim3 gcvt3((int)(SBE / 4 / 256), 1, 3);
    cvt3_f32_to_bf16<<<gcvt3, blk, 0, stream>>>(q_in, k_in, v_in, qkvb, (int)(SBE / 4));
    dim3 gcvt4((int)(EE / 4 / 256), 1, 4);
    cvt4_f32_to_bf16<<<gcvt4, blk, 0, stream>>>(Wq, Wk, Wv, Wo, Wb, (int)(EE / 4));

    // 2. WvT = Wv^T ; Wvo = Wo @ Wv (B^T GEMM with B=WvT) ; bout = Wo bv + bo
    dim3 gtw(16, 16, 1);
    transpose_bf16<<<gtw, blk, 0, stream>>>((const unsigned short*)(Wb + 2 * EE),
                                            (unsigned short*)WvT, E, E);
    dim3 gwvo(E / 128, E / 128, 1);
    gemm_bt128<0><<<gwvo, blk, 0, stream>>>(Wob, WvT, nullptr, nullptr, nullptr,
                                            Wvo, E, E, E, 0, 0, 0, 1.f);
    bias_fold<<<256, blk, 0, stream>>>(Wo, bv, bo, bout);

    // 3. fused projections: z=0 Q (bq), z=1 K (bk), z=2 VW = v_in @ Wvo^T
    dim3 gproj(E / 128, (B * S) / 128, 3);
    gemm_bt128<0><<<gproj, blk, 0, stream>>>(qkvb, Wb, bq, bk, nullptr, QKVb,
                                             B * S, E, E,
                                             (long long)SBE, (long long)EE,
                                             (long long)SBE, 1.f);

    // 4. VW^T per batch: [S,E] -> [E,S]
    dim3 gt(E / 64, S / 64, B);
    transpose_bf16<<<gt, blk, 0, stream>>>((const unsigned short*)VW,
                                           (unsigned short*)VWt, S, E);

    // 5. scores = Q K^T / 32 -> bf16 (balanced causal skip)
    dim3 gsc(S / 64, S / 128, B);
    gemm_bt64<0><<<gsc, blk, 0, stream>>>(Qb, Kb, nullptr, Sc, S, S, E,
                                          (long long)S * E, (long long)S * E,
                                          (long long)S * S, 0.03125f, 1);

    // 6. causal softmax -> bf16 probs (zeros above diagonal)
    softmax_causal<<<B * S, blk, 0, stream>>>(Sc, Pb, S);

    // 7. out = P @ VW + bout (K trimmed causally, fp32 to d_out)
    dim3 gpv(E / 64, S / 128, B);
    gemm_bt64<1><<<gpv, blk, 0, stream>>>(Pb, VWt, bout, (float*)d_out, S, E, S,
                                          (long long)S * S, (long long)E * S,
                                          (long long)S * E, 1.f, 2);
}